// Round 1
// baseline (935.168 us; speedup 1.0000x reference)
//
#include <hip/hip_runtime.h>
#include <stdint.h>

#define TOKENS 4096
#define DMODEL 1024
#define VOCAB  32000
#define KSEL   128

#define BM 128
#define BN 128
#define BK 64

#define NB  2048   // histogram bins
#define CAP 2048   // gather capacity

typedef __attribute__((ext_vector_type(8))) short short8;
typedef __attribute__((ext_vector_type(4))) float f32x4;

__device__ __forceinline__ unsigned short f2bf(float f) {
  uint32_t u = __float_as_uint(f);
  uint32_t r = (u + 0x7fffu + ((u >> 16) & 1u)) >> 16;
  return (unsigned short)r;
}

// ---------------- fp32 -> bf16 cast + fp32 row sum-of-squares ----------------
__global__ __launch_bounds__(256)
void conv_rows(const float* __restrict__ src, unsigned short* __restrict__ dst,
               float* __restrict__ sq, int nrows) {
  int row = blockIdx.x;
  int t = threadIdx.x;
  const float4* s4 = (const float4*)(src + (size_t)row * DMODEL);
  float4 v = s4[t];                      // DMODEL/4 == 256 == blockDim
  float ss = v.x*v.x + v.y*v.y + v.z*v.z + v.w*v.w;
  uint2 pk;
  pk.x = (uint32_t)f2bf(v.x) | ((uint32_t)f2bf(v.y) << 16);
  pk.y = (uint32_t)f2bf(v.z) | ((uint32_t)f2bf(v.w) << 16);
  ((uint2*)(dst + (size_t)row * DMODEL))[t] = pk;

  __shared__ float red[256];
  red[t] = ss; __syncthreads();
  for (int s = 128; s > 0; s >>= 1) {
    if (t < s) red[t] += red[t + s];
    __syncthreads();
  }
  if (t == 0) sq[row] = red[0];
}

// ---------------- bf16 MFMA GEMM with fused distance epilogue ----------------
// dist[rowL][v] = xsq[row] + bsq[v] - 2 * (x . w)
__global__ __launch_bounds__(256)
void gemm_dist(const unsigned short* __restrict__ Xb,
               const unsigned short* __restrict__ Wb,
               const float* __restrict__ xsq, const float* __restrict__ bsq,
               float* __restrict__ dist, int row0) {
  __shared__ unsigned short As[BM * BK];   // 16 KB, row-major [128][64]
  __shared__ unsigned short Bs[BN * BK];   // 16 KB

  int tid  = threadIdx.x;
  int lane = tid & 63;
  int wid  = tid >> 6;        // 4 waves, 2x2
  int wr   = wid >> 1;
  int wc   = wid & 1;
  int bm   = blockIdx.y;
  int bn   = blockIdx.x;
  int rowBase = row0 + bm * BM;       // global token row base
  int colBase = bn * BN;              // vocab base

  f32x4 acc[4][4];
#pragma unroll
  for (int m = 0; m < 4; m++)
#pragma unroll
    for (int n = 0; n < 4; n++) acc[m][n] = (f32x4){0.f, 0.f, 0.f, 0.f};

  const unsigned short* Ag = Xb + (size_t)rowBase * DMODEL;
  const unsigned short* Bg = Wb + (size_t)colBase * DMODEL;

  int r16 = lane & 15;
  int kg  = lane >> 4;

  for (int kt = 0; kt < DMODEL; kt += BK) {
    // stage 128x64 bf16 A and B tiles via async global->LDS, 16B/lane
#pragma unroll
    for (int c = 0; c < 4; c++) {
      int g   = (c * 4 + wid) * 64 + lane;   // 16B granule id, 0..1023
      int r   = g >> 3;                      // tile row 0..127
      int col = (g & 7) * 8;                 // tile col (bf16 elems)
      const unsigned short* ga = Ag + (size_t)r * DMODEL + kt + col;
      const unsigned short* gb = Bg + (size_t)r * DMODEL + kt + col;
      int chunkElems = (c * 4 + wid) * 512;  // wave-uniform LDS chunk base
      __builtin_amdgcn_global_load_lds(
          (const __attribute__((address_space(1))) void*)ga,
          (__attribute__((address_space(3))) void*)(&As[chunkElems]), 16, 0, 0);
      __builtin_amdgcn_global_load_lds(
          (const __attribute__((address_space(1))) void*)gb,
          (__attribute__((address_space(3))) void*)(&Bs[chunkElems]), 16, 0, 0);
    }
    __syncthreads();

#pragma unroll
    for (int kk = 0; kk < BK; kk += 32) {
      short8 a[4], b[4];
#pragma unroll
      for (int m = 0; m < 4; m++)
        a[m] = *(const short8*)&As[(wr * 64 + m * 16 + r16) * BK + kk + kg * 8];
#pragma unroll
      for (int n = 0; n < 4; n++)
        b[n] = *(const short8*)&Bs[(wc * 64 + n * 16 + r16) * BK + kk + kg * 8];
#pragma unroll
      for (int m = 0; m < 4; m++)
#pragma unroll
        for (int n = 0; n < 4; n++)
          acc[m][n] = __builtin_amdgcn_mfma_f32_16x16x32_bf16(a[m], b[n], acc[m][n], 0, 0, 0);
    }
    __syncthreads();
  }

  // epilogue: C/D layout col=lane&15, row=(lane>>4)*4+i
  int col16 = lane & 15;
  int rg    = lane >> 4;
#pragma unroll
  for (int m = 0; m < 4; m++) {
#pragma unroll
    for (int n = 0; n < 4; n++) {
      int col = colBase + wc * 64 + n * 16 + col16;
      float bq = bsq[col];
#pragma unroll
      for (int i = 0; i < 4; i++) {
        int rowL = bm * BM + wr * 64 + m * 16 + rg * 4 + i;  // slab-local row
        float d = xsq[row0 + rowL] + bq - 2.0f * acc[m][n][i];
        dist[(size_t)rowL * VOCAB + col] = d;
      }
    }
  }
}

// ---------------- per-row 128-smallest, sorted ascending ----------------
__device__ __forceinline__ int binOf(float x, float mn, float invw) {
  int b = (int)((x - mn) * invw);
  return b < NB - 1 ? b : NB - 1;
}

__device__ __forceinline__ void scanFind(unsigned* bins, unsigned* s_scan,
                                         unsigned target, int* s_B,
                                         unsigned* s_cum, int t) {
  unsigned ssum = 0;
  int base = t * (NB / 256);
#pragma unroll
  for (int j = 0; j < NB / 256; j++) ssum += bins[base + j];
  s_scan[t] = ssum;
  __syncthreads();
  for (int off = 1; off < 256; off <<= 1) {
    unsigned add = (t >= off) ? s_scan[t - off] : 0u;
    __syncthreads();
    s_scan[t] += add;
    __syncthreads();
  }
  unsigned incl = s_scan[t];
  unsigned excl = incl - ssum;
  if (excl < target && incl >= target) {
    unsigned cum = excl;
    for (int j = 0; j < NB / 256; j++) {
      cum += bins[base + j];
      if (cum >= target) { *s_B = base + j; *s_cum = cum; break; }
    }
  }
  __syncthreads();
}

__global__ __launch_bounds__(256)
void select_topk(const float* __restrict__ dist, float* __restrict__ out, int row0) {
  int r = blockIdx.x;
  int t = threadIdx.x;
  const float* rowp = dist + (size_t)r * VOCAB;

  __shared__ float    s_red[256];
  __shared__ float    s_red2[256];
  __shared__ unsigned s_scan[256];
  __shared__ unsigned bins[NB];
  __shared__ float    cand[CAP];
  __shared__ unsigned s_cnt;
  __shared__ int      s_B, s_B2;
  __shared__ unsigned s_cum, s_cum2;

  // pass 1: row min/max
  float mn = 3.4e38f, mx = -3.4e38f;
  for (int i = t; i < VOCAB / 4; i += 256) {
    float4 v = ((const float4*)rowp)[i];
    mn = fminf(mn, fminf(fminf(v.x, v.y), fminf(v.z, v.w)));
    mx = fmaxf(mx, fmaxf(fmaxf(v.x, v.y), fmaxf(v.z, v.w)));
  }
  s_red[t] = mn; s_red2[t] = mx; __syncthreads();
  for (int s = 128; s > 0; s >>= 1) {
    if (t < s) {
      s_red[t]  = fminf(s_red[t],  s_red[t + s]);
      s_red2[t] = fmaxf(s_red2[t], s_red2[t + s]);
    }
    __syncthreads();
  }
  float rmn = s_red[0], rmx = s_red2[0];
  float range = rmx - rmn;

  if (!(range > 1e-20f)) {   // degenerate: all values equal
    for (int i = t; i < KSEL; i += 256)
      out[(size_t)(row0 + r) * KSEL + i] = rmn;
    return;
  }

  float invw = (float)NB / range;

  // pass 2: histogram
  for (int i = t; i < NB; i += 256) bins[i] = 0;
  __syncthreads();
  for (int i = t; i < VOCAB / 4; i += 256) {
    float4 v = ((const float4*)rowp)[i];
    atomicAdd(&bins[binOf(v.x, rmn, invw)], 1u);
    atomicAdd(&bins[binOf(v.y, rmn, invw)], 1u);
    atomicAdd(&bins[binOf(v.z, rmn, invw)], 1u);
    atomicAdd(&bins[binOf(v.w, rmn, invw)], 1u);
  }
  __syncthreads();

  scanFind(bins, s_scan, KSEL, &s_B, &s_cum, t);
  int B = s_B;
  unsigned cntLE = s_cum;
  unsigned below = cntLE - bins[B];
  __syncthreads();

  // optional one-level refinement if threshold bin is fat
  bool refine = (cntLE > CAP);
  float lo2 = rmn + (float)B * (range / (float)NB);
  float inv2 = invw * (float)NB;   // NB / (range/NB)
  int B2 = 0;
  if (refine) {
    for (int i = t; i < NB; i += 256) bins[i] = 0;
    __syncthreads();
    for (int i = t; i < VOCAB; i += 256) {
      float x = rowp[i];
      if (binOf(x, rmn, invw) == B) {
        int b2 = (int)((x - lo2) * inv2);
        b2 = b2 < 0 ? 0 : (b2 > NB - 1 ? NB - 1 : b2);
        atomicAdd(&bins[b2], 1u);
      }
    }
    __syncthreads();
    scanFind(bins, s_scan, KSEL - below, &s_B2, &s_cum2, t);
    B2 = s_B2;
    __syncthreads();
  }

  // gather candidates
  if (t == 0) s_cnt = 0;
  __syncthreads();
  for (int i = t; i < VOCAB; i += 256) {
    float x = rowp[i];
    int b = binOf(x, rmn, invw);
    bool take;
    if (!refine) {
      take = (b <= B);
    } else {
      if (b < B) take = true;
      else if (b == B) {
        int b2 = (int)((x - lo2) * inv2);
        b2 = b2 < 0 ? 0 : (b2 > NB - 1 ? NB - 1 : b2);
        take = (b2 <= B2);
      } else take = false;
    }
    if (take) {
      unsigned idx = atomicAdd(&s_cnt, 1u);
      if (idx < CAP) cand[idx] = x;
    }
  }
  __syncthreads();
  int m = (int)(s_cnt < CAP ? s_cnt : CAP);

  // rank + scatter (ascending). ranks are unique via index tie-break.
  for (int i = t; i < m; i += 256) {
    float vi = cand[i];
    int rk = 0;
    for (int j = 0; j < m; j++) {
      float vj = cand[j];
      rk += (vj < vi) || (vj == vi && j < i);
    }
    if (rk < KSEL) out[(size_t)(row0 + r) * KSEL + rk] = vi;
  }
}

extern "C" void kernel_launch(void* const* d_in, const int* in_sizes, int n_in,
                              void* d_out, int out_size, void* d_ws, size_t ws_size,
                              hipStream_t stream) {
  const float* x = (const float*)d_in[0];
  const float* w = (const float*)d_in[1];
  float* out = (float*)d_out;

  char* ws = (char*)d_ws;
  size_t off = 0;
  auto alloc = [&](size_t bytes) -> char* {
    off = (off + 255) & ~(size_t)255;
    char* p = ws + off;
    off += bytes;
    return p;
  };
  unsigned short* Xb = (unsigned short*)alloc((size_t)TOKENS * DMODEL * 2);
  unsigned short* Wb = (unsigned short*)alloc((size_t)VOCAB * DMODEL * 2);
  float* xsq = (float*)alloc((size_t)TOKENS * 4);
  float* bsq = (float*)alloc((size_t)VOCAB * 4);
  off = (off + 255) & ~(size_t)255;
  size_t fixed = off;

  // pick token-slab size that fits ws (dist slab = TS * VOCAB * 4 bytes)
  int TS = TOKENS;
  while (TS > 128 && fixed + (size_t)TS * VOCAB * 4 > ws_size) TS >>= 1;
  float* dist = (float*)(ws + fixed);

  conv_rows<<<TOKENS, 256, 0, stream>>>(x, Xb, xsq, TOKENS);
  conv_rows<<<VOCAB, 256, 0, stream>>>(w, Wb, bsq, VOCAB);

  for (int row0 = 0; row0 < TOKENS; row0 += TS) {
    dim3 g(VOCAB / BN, TS / BM);
    gemm_dist<<<g, 256, 0, stream>>>(Xb, Wb, xsq, bsq, dist, row0);
    select_topk<<<TS, 256, 0, stream>>>(dist, out, row0);
  }
}

// Round 2
// 801.754 us; speedup vs baseline: 1.1664x; 1.1664x over previous
//
#include <hip/hip_runtime.h>
#include <stdint.h>

#define TOKENS 4096
#define DMODEL 1024
#define VOCAB  32000
#define KSEL   128

#define BM 128
#define BN 128
#define BK 64

#define NB  2048   // histogram bins
#define CAP 2048   // gather capacity

typedef __attribute__((ext_vector_type(8))) short short8;
typedef __attribute__((ext_vector_type(4))) float f32x4;

__device__ __forceinline__ unsigned short f2bf(float f) {
  uint32_t u = __float_as_uint(f);
  uint32_t r = (u + 0x7fffu + ((u >> 16) & 1u)) >> 16;
  return (unsigned short)r;
}
// order-preserving float<->uint for atomicMin/Max
__device__ __forceinline__ unsigned encf(float f) {
  unsigned u = __float_as_uint(f);
  return (u >> 31) ? ~u : (u | 0x80000000u);
}
__device__ __forceinline__ float decf(unsigned e) {
  return __uint_as_float((e >> 31) ? (e & 0x7fffffffu) : ~e);
}

// ---------------- fp32 -> bf16 cast + fp32 row sum-of-squares ----------------
__global__ __launch_bounds__(256)
void conv_rows(const float* __restrict__ src, unsigned short* __restrict__ dst,
               float* __restrict__ sq, int nrows) {
  int row = blockIdx.x;
  int t = threadIdx.x;
  const float4* s4 = (const float4*)(src + (size_t)row * DMODEL);
  float4 v = s4[t];                      // DMODEL/4 == 256 == blockDim
  float ss = v.x*v.x + v.y*v.y + v.z*v.z + v.w*v.w;
  uint2 pk;
  pk.x = (uint32_t)f2bf(v.x) | ((uint32_t)f2bf(v.y) << 16);
  pk.y = (uint32_t)f2bf(v.z) | ((uint32_t)f2bf(v.w) << 16);
  ((uint2*)(dst + (size_t)row * DMODEL))[t] = pk;

  __shared__ float red[256];
  red[t] = ss; __syncthreads();
  for (int s = 128; s > 0; s >>= 1) {
    if (t < s) red[t] += red[t + s];
    __syncthreads();
  }
  if (t == 0) sq[row] = red[0];
}

// ---------------- bf16 MFMA GEMM with fused distance epilogue ----------------
// dist[rowL][v] = bf16( xsq[row] + bsq[v] - 2 * (x . w) ), plus per-row min/max
__global__ __launch_bounds__(256)
void gemm_dist(const unsigned short* __restrict__ Xb,
               const unsigned short* __restrict__ Wb,
               const float* __restrict__ xsq, const float* __restrict__ bsq,
               unsigned short* __restrict__ dist,
               unsigned* __restrict__ rminE, unsigned* __restrict__ rmaxE,
               int row0) {
  __shared__ unsigned short As[BM * BK];   // 16 KB, row-major [128][64]
  __shared__ unsigned short Bs[BN * BK];   // 16 KB
  __shared__ unsigned rminS[BM], rmaxS[BM];

  int tid  = threadIdx.x;
  int lane = tid & 63;
  int wid  = tid >> 6;        // 4 waves, 2x2
  int wr   = wid >> 1;
  int wc   = wid & 1;

  // ---- XCD-aware bijective swizzle + 4-row supertiles ----
  int nwg = gridDim.x * gridDim.y;               // multiple of 8 for all TS
  int bid = blockIdx.y * gridDim.x + blockIdx.x;
  int cpx = nwg >> 3;
  int o   = (bid & 7) * cpx + (bid >> 3);        // bijective (nwg%8==0)
  int NR  = gridDim.y;
  int GR  = (NR & 3) ? 1 : 4;                    // row-group size
  int span = gridDim.x * GR;
  int sg  = o / span;
  int rem = o - sg * span;
  int bn  = rem / GR;
  int bm  = sg * GR + (rem - bn * GR);

  int rowBase = row0 + bm * BM;       // global token row base
  int colBase = bn * BN;              // vocab base

  for (int i = tid; i < BM; i += 256) { rminS[i] = 0xFFFFFFFFu; rmaxS[i] = 0u; }

  f32x4 acc[4][4];
#pragma unroll
  for (int m = 0; m < 4; m++)
#pragma unroll
    for (int n = 0; n < 4; n++) acc[m][n] = (f32x4){0.f, 0.f, 0.f, 0.f};

  const unsigned short* Ag = Xb + (size_t)rowBase * DMODEL;
  const unsigned short* Bg = Wb + (size_t)colBase * DMODEL;

  int r16 = lane & 15;
  int kg  = lane >> 4;

  for (int kt = 0; kt < DMODEL; kt += BK) {
    // stage 128x64 bf16 A and B tiles via async global->LDS, 16B/lane
#pragma unroll
    for (int c = 0; c < 4; c++) {
      int g   = (c * 4 + wid) * 64 + lane;   // 16B granule id, 0..1023
      int r   = g >> 3;                      // tile row 0..127
      int col = (g & 7) * 8;                 // tile col (bf16 elems)
      const unsigned short* ga = Ag + (size_t)r * DMODEL + kt + col;
      const unsigned short* gb = Bg + (size_t)r * DMODEL + kt + col;
      int chunkElems = (c * 4 + wid) * 512;  // wave-uniform LDS chunk base
      __builtin_amdgcn_global_load_lds(
          (const __attribute__((address_space(1))) void*)ga,
          (__attribute__((address_space(3))) void*)(&As[chunkElems]), 16, 0, 0);
      __builtin_amdgcn_global_load_lds(
          (const __attribute__((address_space(1))) void*)gb,
          (__attribute__((address_space(3))) void*)(&Bs[chunkElems]), 16, 0, 0);
    }
    __syncthreads();

#pragma unroll
    for (int kk = 0; kk < BK; kk += 32) {
      short8 a[4], b[4];
#pragma unroll
      for (int m = 0; m < 4; m++)
        a[m] = *(const short8*)&As[(wr * 64 + m * 16 + r16) * BK + kk + kg * 8];
#pragma unroll
      for (int n = 0; n < 4; n++)
        b[n] = *(const short8*)&Bs[(wc * 64 + n * 16 + r16) * BK + kk + kg * 8];
#pragma unroll
      for (int m = 0; m < 4; m++)
#pragma unroll
        for (int n = 0; n < 4; n++)
          acc[m][n] = __builtin_amdgcn_mfma_f32_16x16x32_bf16(a[m], b[n], acc[m][n], 0, 0, 0);
    }
    __syncthreads();
  }

  // epilogue: C/D layout col=lane&15, row=(lane>>4)*4+i
  int col16 = lane & 15;
  int rg    = lane >> 4;
  float bq[4];
#pragma unroll
  for (int n = 0; n < 4; n++) bq[n] = bsq[colBase + wc * 64 + n * 16 + col16];

#pragma unroll
  for (int m = 0; m < 4; m++) {
#pragma unroll
    for (int i = 0; i < 4; i++) {
      int lrow = wr * 64 + m * 16 + rg * 4 + i;       // block-local row
      int rowL = bm * BM + lrow;                      // slab-local row
      float xq = xsq[row0 + rowL];
      float mn = 3.4e38f, mx = -3.4e38f;
#pragma unroll
      for (int n = 0; n < 4; n++) {
        float d = xq + bq[n] - 2.0f * acc[m][n][i];
        unsigned short h = f2bf(d);
        float dr = __uint_as_float((unsigned)h << 16);
        dist[(size_t)rowL * VOCAB + colBase + wc * 64 + n * 16 + col16] = h;
        mn = fminf(mn, dr);
        mx = fmaxf(mx, dr);
      }
      atomicMin(&rminS[lrow], encf(mn));
      atomicMax(&rmaxS[lrow], encf(mx));
    }
  }
  __syncthreads();
  if (tid < BM) {
    atomicMin(&rminE[row0 + bm * BM + tid], rminS[tid]);
    atomicMax(&rmaxE[row0 + bm * BM + tid], rmaxS[tid]);
  }
}

// ---------------- per-row 128-smallest, sorted ascending ----------------
__device__ __forceinline__ int binOf(float x, float mn, float invw) {
  int b = (int)((x - mn) * invw);
  b = b < 0 ? 0 : b;
  return b < NB - 1 ? b : NB - 1;
}

__device__ __forceinline__ void scanFind(unsigned* bins, unsigned* s_scan,
                                         unsigned target, int* s_B,
                                         unsigned* s_cum, int t) {
  unsigned ssum = 0;
  int base = t * (NB / 256);
#pragma unroll
  for (int j = 0; j < NB / 256; j++) ssum += bins[base + j];
  s_scan[t] = ssum;
  __syncthreads();
  for (int off = 1; off < 256; off <<= 1) {
    unsigned add = (t >= off) ? s_scan[t - off] : 0u;
    __syncthreads();
    s_scan[t] += add;
    __syncthreads();
  }
  unsigned incl = s_scan[t];
  unsigned excl = incl - ssum;
  if (excl < target && incl >= target) {
    unsigned cum = excl;
    for (int j = 0; j < NB / 256; j++) {
      cum += bins[base + j];
      if (cum >= target) { *s_B = base + j; *s_cum = cum; break; }
    }
  }
  __syncthreads();
}

__global__ __launch_bounds__(256)
void select_topk(const unsigned short* __restrict__ dist,
                 const unsigned* __restrict__ rminE,
                 const unsigned* __restrict__ rmaxE,
                 float* __restrict__ out, int row0) {
  int r = blockIdx.x;
  int t = threadIdx.x;
  int grow = row0 + r;
  const unsigned short* rowp = dist + (size_t)r * VOCAB;

  __shared__ unsigned s_scan[256];
  __shared__ unsigned bins[NB];
  __shared__ float    cand[CAP];
  __shared__ unsigned s_cnt;
  __shared__ int      s_B;
  __shared__ unsigned s_cum;

  float rmn = decf(rminE[grow]);
  float rmx = decf(rmaxE[grow]);
  float range = rmx - rmn;

  if (!(range > 1e-20f)) {   // degenerate: all values equal
    for (int i = t; i < KSEL; i += 256)
      out[(size_t)grow * KSEL + i] = rmn;
    return;
  }
  float invw = (float)NB / range;

  // pass 1: histogram over bf16 values
  for (int i = t; i < NB; i += 256) bins[i] = 0;
  __syncthreads();
  const uint4* rp4 = (const uint4*)rowp;   // 8 bf16 per load
  for (int i = t; i < VOCAB / 8; i += 256) {
    uint4 u = rp4[i];
    unsigned w[4] = {u.x, u.y, u.z, u.w};
#pragma unroll
    for (int j = 0; j < 4; j++) {
      float lo = __uint_as_float(w[j] << 16);
      float hi = __uint_as_float(w[j] & 0xffff0000u);
      atomicAdd(&bins[binOf(lo, rmn, invw)], 1u);
      atomicAdd(&bins[binOf(hi, rmn, invw)], 1u);
    }
  }
  __syncthreads();

  scanFind(bins, s_scan, KSEL, &s_B, &s_cum, t);
  int B = s_B;

  // pass 2: gather candidates (<= bin B)
  if (t == 0) s_cnt = 0;
  __syncthreads();
  for (int i = t; i < VOCAB / 8; i += 256) {
    uint4 u = rp4[i];
    unsigned w[4] = {u.x, u.y, u.z, u.w};
#pragma unroll
    for (int j = 0; j < 4; j++) {
#pragma unroll
      for (int h = 0; h < 2; h++) {
        float x = __uint_as_float(h ? (w[j] & 0xffff0000u) : (w[j] << 16));
        if (binOf(x, rmn, invw) <= B) {
          unsigned idx = atomicAdd(&s_cnt, 1u);
          if (idx < CAP) cand[idx] = x;
        }
      }
    }
  }
  __syncthreads();
  int m = (int)(s_cnt < CAP ? s_cnt : CAP);

  // rank + scatter (ascending). ranks unique via index tie-break.
  for (int i = t; i < m; i += 256) {
    float vi = cand[i];
    int rk = 0;
    for (int j = 0; j < m; j++) {
      float vj = cand[j];
      rk += (vj < vi) || (vj == vi && j < i);
    }
    if (rk < KSEL) out[(size_t)grow * KSEL + rk] = vi;
  }
}

extern "C" void kernel_launch(void* const* d_in, const int* in_sizes, int n_in,
                              void* d_out, int out_size, void* d_ws, size_t ws_size,
                              hipStream_t stream) {
  const float* x = (const float*)d_in[0];
  const float* w = (const float*)d_in[1];
  float* out = (float*)d_out;

  char* ws = (char*)d_ws;
  size_t off = 0;
  auto alloc = [&](size_t bytes) -> char* {
    off = (off + 255) & ~(size_t)255;
    char* p = ws + off;
    off += bytes;
    return p;
  };
  unsigned short* Xb = (unsigned short*)alloc((size_t)TOKENS * DMODEL * 2);
  unsigned short* Wb = (unsigned short*)alloc((size_t)VOCAB * DMODEL * 2);
  float* xsq = (float*)alloc((size_t)TOKENS * 4);
  float* bsq = (float*)alloc((size_t)VOCAB * 4);
  unsigned* rminE = (unsigned*)alloc((size_t)TOKENS * 4);
  unsigned* rmaxE = (unsigned*)alloc((size_t)TOKENS * 4);
  off = (off + 255) & ~(size_t)255;
  size_t fixed = off;

  // pick token-slab size that fits ws (dist slab = TS * VOCAB * 2 bytes, bf16)
  int TS = TOKENS;
  while (TS > 128 && fixed + (size_t)TS * VOCAB * 2 > ws_size) TS >>= 1;
  unsigned short* dist = (unsigned short*)(ws + fixed);

  hipMemsetAsync(rminE, 0xFF, (size_t)TOKENS * 4, stream);   // +inf encoding
  hipMemsetAsync(rmaxE, 0x00, (size_t)TOKENS * 4, stream);   // -inf encoding

  conv_rows<<<TOKENS, 256, 0, stream>>>(x, Xb, xsq, TOKENS);
  conv_rows<<<VOCAB, 256, 0, stream>>>(w, Wb, bsq, VOCAB);

  for (int row0 = 0; row0 < TOKENS; row0 += TS) {
    dim3 g(VOCAB / BN, TS / BM);
    gemm_dist<<<g, 256, 0, stream>>>(Xb, Wb, xsq, bsq, dist, rminE, rmaxE, row0);
    select_topk<<<TS, 256, 0, stream>>>(dist, rminE, rmaxE, out, row0);
  }
}

// Round 3
// 750.267 us; speedup vs baseline: 1.2464x; 1.0686x over previous
//
#include <hip/hip_runtime.h>
#include <stdint.h>

#define TOKENS 4096
#define DMODEL 1024
#define VOCAB  32000
#define KSEL   128

#define BM 128
#define BN 128
#define BK 64

#define NB  2048   // histogram bins
#define CAP 2048   // gather capacity

typedef __attribute__((ext_vector_type(8))) short short8;
typedef __attribute__((ext_vector_type(4))) float f32x4;

__device__ __forceinline__ unsigned short f2bf(float f) {
  uint32_t u = __float_as_uint(f);
  uint32_t r = (u + 0x7fffu + ((u >> 16) & 1u)) >> 16;
  return (unsigned short)r;
}
// order-preserving float<->uint for atomicMin/Max
__device__ __forceinline__ unsigned encf(float f) {
  unsigned u = __float_as_uint(f);
  return (u >> 31) ? ~u : (u | 0x80000000u);
}
__device__ __forceinline__ float decf(unsigned e) {
  return __uint_as_float((e >> 31) ? (e & 0x7fffffffu) : ~e);
}

// ---------------- fp32 -> bf16 cast + fp32 row sum-of-squares ----------------
__global__ __launch_bounds__(256)
void conv_rows(const float* __restrict__ src, unsigned short* __restrict__ dst,
               float* __restrict__ sq, int nrows) {
  int row = blockIdx.x;
  int t = threadIdx.x;
  const float4* s4 = (const float4*)(src + (size_t)row * DMODEL);
  float4 v = s4[t];                      // DMODEL/4 == 256 == blockDim
  float ss = v.x*v.x + v.y*v.y + v.z*v.z + v.w*v.w;
  uint2 pk;
  pk.x = (uint32_t)f2bf(v.x) | ((uint32_t)f2bf(v.y) << 16);
  pk.y = (uint32_t)f2bf(v.z) | ((uint32_t)f2bf(v.w) << 16);
  ((uint2*)(dst + (size_t)row * DMODEL))[t] = pk;

  __shared__ float red[256];
  red[t] = ss; __syncthreads();
  for (int s = 128; s > 0; s >>= 1) {
    if (t < s) red[t] += red[t + s];
    __syncthreads();
  }
  if (t == 0) sq[row] = red[0];
}

// ---------------- bf16 MFMA GEMM with fused distance epilogue ----------------
// dist[rowL][v] = bf16( xsq[row] + bsq[v] - 2 * (x . w) ), plus GLOBAL min/max
__global__ __launch_bounds__(256)
void gemm_dist(const unsigned short* __restrict__ Xb,
               const unsigned short* __restrict__ Wb,
               const float* __restrict__ xsq, const float* __restrict__ bsq,
               unsigned short* __restrict__ dist,
               unsigned* __restrict__ gmnE, unsigned* __restrict__ gmxE,
               int row0) {
  __shared__ unsigned short S[BM * BK * 2];   // 32 KB: A|B tiles, then C restage
  unsigned short* As = S;
  unsigned short* Bs = S + BM * BK;
  __shared__ unsigned wmn[4], wmx[4];

  int tid  = threadIdx.x;
  int lane = tid & 63;
  int wid  = tid >> 6;        // 4 waves, 2x2
  int wr   = wid >> 1;
  int wc   = wid & 1;

  // ---- XCD-aware bijective swizzle + 4-row supertiles ----
  int nwg = gridDim.x * gridDim.y;               // multiple of 8 for all TS
  int bid = blockIdx.y * gridDim.x + blockIdx.x;
  int cpx = nwg >> 3;
  int o   = (bid & 7) * cpx + (bid >> 3);        // bijective (nwg%8==0)
  int NR  = gridDim.y;
  int GR  = (NR & 3) ? 1 : 4;                    // row-group size
  int span = gridDim.x * GR;
  int sg  = o / span;
  int rem = o - sg * span;
  int bn  = rem / GR;
  int bm  = sg * GR + (rem - bn * GR);

  int rowBase = row0 + bm * BM;       // global token row base
  int colBase = bn * BN;              // vocab base

  f32x4 acc[4][4];
#pragma unroll
  for (int m = 0; m < 4; m++)
#pragma unroll
    for (int n = 0; n < 4; n++) acc[m][n] = (f32x4){0.f, 0.f, 0.f, 0.f};

  const unsigned short* Ag = Xb + (size_t)rowBase * DMODEL;
  const unsigned short* Bg = Wb + (size_t)colBase * DMODEL;

  int r16 = lane & 15;
  int kg  = lane >> 4;

  for (int kt = 0; kt < DMODEL; kt += BK) {
    // stage 128x64 bf16 A and B tiles via async global->LDS, 16B/lane
#pragma unroll
    for (int c = 0; c < 4; c++) {
      int g   = (c * 4 + wid) * 64 + lane;   // 16B granule id, 0..1023
      int r   = g >> 3;                      // tile row 0..127
      int col = (g & 7) * 8;                 // tile col (bf16 elems)
      const unsigned short* ga = Ag + (size_t)r * DMODEL + kt + col;
      const unsigned short* gb = Bg + (size_t)r * DMODEL + kt + col;
      int chunkElems = (c * 4 + wid) * 512;  // wave-uniform LDS chunk base
      __builtin_amdgcn_global_load_lds(
          (const __attribute__((address_space(1))) void*)ga,
          (__attribute__((address_space(3))) void*)(&As[chunkElems]), 16, 0, 0);
      __builtin_amdgcn_global_load_lds(
          (const __attribute__((address_space(1))) void*)gb,
          (__attribute__((address_space(3))) void*)(&Bs[chunkElems]), 16, 0, 0);
    }
    __syncthreads();

#pragma unroll
    for (int kk = 0; kk < BK; kk += 32) {
      short8 a[4], b[4];
#pragma unroll
      for (int m = 0; m < 4; m++)
        a[m] = *(const short8*)&As[(wr * 64 + m * 16 + r16) * BK + kk + kg * 8];
#pragma unroll
      for (int n = 0; n < 4; n++)
        b[n] = *(const short8*)&Bs[(wc * 64 + n * 16 + r16) * BK + kk + kg * 8];
#pragma unroll
      for (int m = 0; m < 4; m++)
#pragma unroll
        for (int n = 0; n < 4; n++)
          acc[m][n] = __builtin_amdgcn_mfma_f32_16x16x32_bf16(a[m], b[n], acc[m][n], 0, 0, 0);
    }
    __syncthreads();
  }

  // ---- epilogue: distances -> bf16 into LDS (swizzled), track min/max ----
  // C/D layout: col=lane&15, row=(lane>>4)*4+i
  int col16 = lane & 15;
  int rg    = lane >> 4;
  float bq[4];
#pragma unroll
  for (int n = 0; n < 4; n++) bq[n] = bsq[colBase + wc * 64 + n * 16 + col16];

  float mnT = 3.4e38f, mxT = -3.4e38f;
#pragma unroll
  for (int m = 0; m < 4; m++) {
#pragma unroll
    for (int i = 0; i < 4; i++) {
      int row = wr * 64 + m * 16 + rg * 4 + i;        // block-local row
      float xq = xsq[rowBase + row];
#pragma unroll
      for (int n = 0; n < 4; n++) {
        float d = xq + bq[n] - 2.0f * acc[m][n][i];
        unsigned short h = f2bf(d);
        float dr = __uint_as_float((unsigned)h << 16);
        mnT = fminf(mnT, dr);
        mxT = fmaxf(mxT, dr);
        int col = wc * 64 + n * 16 + col16;
        int byte = (row << 8) + (col << 1);
        byte ^= (row & 12) << 3;                      // bank swizzle
        *(unsigned short*)((char*)S + byte) = h;
      }
    }
  }
#pragma unroll
  for (int off = 32; off; off >>= 1) {
    mnT = fminf(mnT, __shfl_xor(mnT, off));
    mxT = fmaxf(mxT, __shfl_xor(mxT, off));
  }
  if (lane == 0) { wmn[wid] = encf(mnT); wmx[wid] = encf(mxT); }
  __syncthreads();
  if (tid == 0) {
    unsigned a = min(min(wmn[0], wmn[1]), min(wmn[2], wmn[3]));
    unsigned b = max(max(wmx[0], wmx[1]), max(wmx[2], wmx[3]));
    atomicMin(gmnE, a);
    atomicMax(gmxE, b);
  }

  // ---- coalesced 16B stores from LDS ----
  size_t gbase = (size_t)(bm * BM) * VOCAB + colBase;
#pragma unroll
  for (int c = 0; c < 8; c++) {
    int g   = c * 256 + tid;            // 16B granule, 0..2047
    int row = g >> 4;
    int byte = (row << 8) + ((g & 15) << 4);
    byte ^= (row & 12) << 3;
    uint4 v = *(const uint4*)((const char*)S + byte);
    *(uint4*)(dist + gbase + (size_t)row * VOCAB + ((g & 15) << 3)) = v;
  }
}

// ---------------- per-row 128-smallest, sorted ascending ----------------
__device__ __forceinline__ int binOf(float x, float mn, float invw) {
  int b = (int)((x - mn) * invw);
  b = b < 0 ? 0 : b;
  return b < NB - 1 ? b : NB - 1;
}

__device__ __forceinline__ void scanFind(unsigned* bins, unsigned* s_scan,
                                         unsigned target, int* s_B,
                                         unsigned* s_cum, int t) {
  unsigned ssum = 0;
  int base = t * (NB / 256);
#pragma unroll
  for (int j = 0; j < NB / 256; j++) ssum += bins[base + j];
  s_scan[t] = ssum;
  __syncthreads();
  for (int off = 1; off < 256; off <<= 1) {
    unsigned add = (t >= off) ? s_scan[t - off] : 0u;
    __syncthreads();
    s_scan[t] += add;
    __syncthreads();
  }
  unsigned incl = s_scan[t];
  unsigned excl = incl - ssum;
  if (excl < target && incl >= target) {
    unsigned cum = excl;
    for (int j = 0; j < NB / 256; j++) {
      cum += bins[base + j];
      if (cum >= target) { *s_B = base + j; *s_cum = cum; break; }
    }
  }
  __syncthreads();
}

__global__ __launch_bounds__(256)
void select_topk(const unsigned short* __restrict__ dist,
                 const unsigned* __restrict__ gmnE,
                 const unsigned* __restrict__ gmxE,
                 float* __restrict__ out, int row0) {
  int r = blockIdx.x;
  int t = threadIdx.x;
  int grow = row0 + r;
  const unsigned short* rowp = dist + (size_t)r * VOCAB;

  __shared__ unsigned s_scan[256];
  __shared__ unsigned bins[NB];
  __shared__ float    cand[CAP];
  __shared__ unsigned s_cnt;
  __shared__ int      s_B;
  __shared__ unsigned s_cum;

  float rmn = decf(gmnE[0]);
  float rmx = decf(gmxE[0]);
  float range = rmx - rmn;

  if (!(range > 1e-20f)) {   // degenerate: all values equal
    for (int i = t; i < KSEL; i += 256)
      out[(size_t)grow * KSEL + i] = rmn;
    return;
  }
  float invw = (float)NB / range;

  // pass 1: histogram over bf16 values
  for (int i = t; i < NB; i += 256) bins[i] = 0;
  __syncthreads();
  const uint4* rp4 = (const uint4*)rowp;   // 8 bf16 per load
  for (int i = t; i < VOCAB / 8; i += 256) {
    uint4 u = rp4[i];
    unsigned w[4] = {u.x, u.y, u.z, u.w};
#pragma unroll
    for (int j = 0; j < 4; j++) {
      float lo = __uint_as_float(w[j] << 16);
      float hi = __uint_as_float(w[j] & 0xffff0000u);
      atomicAdd(&bins[binOf(lo, rmn, invw)], 1u);
      atomicAdd(&bins[binOf(hi, rmn, invw)], 1u);
    }
  }
  __syncthreads();

  scanFind(bins, s_scan, KSEL, &s_B, &s_cum, t);
  int B = s_B;

  // pass 2: gather candidates (<= bin B)
  if (t == 0) s_cnt = 0;
  __syncthreads();
  for (int i = t; i < VOCAB / 8; i += 256) {
    uint4 u = rp4[i];
    unsigned w[4] = {u.x, u.y, u.z, u.w};
#pragma unroll
    for (int j = 0; j < 4; j++) {
#pragma unroll
      for (int h = 0; h < 2; h++) {
        float x = __uint_as_float(h ? (w[j] & 0xffff0000u) : (w[j] << 16));
        if (binOf(x, rmn, invw) <= B) {
          unsigned idx = atomicAdd(&s_cnt, 1u);
          if (idx < CAP) cand[idx] = x;
        }
      }
    }
  }
  __syncthreads();
  int m = (int)(s_cnt < CAP ? s_cnt : CAP);

  // rank + scatter (ascending). ranks unique via index tie-break.
  for (int i = t; i < m; i += 256) {
    float vi = cand[i];
    int rk = 0;
    for (int j = 0; j < m; j++) {
      float vj = cand[j];
      rk += (vj < vi) || (vj == vi && j < i);
    }
    if (rk < KSEL) out[(size_t)grow * KSEL + rk] = vi;
  }
}

extern "C" void kernel_launch(void* const* d_in, const int* in_sizes, int n_in,
                              void* d_out, int out_size, void* d_ws, size_t ws_size,
                              hipStream_t stream) {
  const float* x = (const float*)d_in[0];
  const float* w = (const float*)d_in[1];
  float* out = (float*)d_out;

  char* ws = (char*)d_ws;
  size_t off = 0;
  auto alloc = [&](size_t bytes) -> char* {
    off = (off + 255) & ~(size_t)255;
    char* p = ws + off;
    off += bytes;
    return p;
  };
  unsigned short* Xb = (unsigned short*)alloc((size_t)TOKENS * DMODEL * 2);
  unsigned short* Wb = (unsigned short*)alloc((size_t)VOCAB * DMODEL * 2);
  float* xsq = (float*)alloc((size_t)TOKENS * 4);
  float* bsq = (float*)alloc((size_t)VOCAB * 4);
  unsigned* gmnE = (unsigned*)alloc(4);
  unsigned* gmxE = (unsigned*)alloc(4);
  off = (off + 255) & ~(size_t)255;
  size_t fixed = off;

  // dist slab: TS * VOCAB * 2 bytes (bf16). TS=2048 keeps slab (131 MB) L3-resident.
  int TS = 2048;
  while (TS > 128 && fixed + (size_t)TS * VOCAB * 2 > ws_size) TS >>= 1;
  unsigned short* dist = (unsigned short*)(ws + fixed);

  hipMemsetAsync(gmnE, 0xFF, 4, stream);   // +inf encoding
  hipMemsetAsync(gmxE, 0x00, 4, stream);   // -inf encoding

  conv_rows<<<TOKENS, 256, 0, stream>>>(x, Xb, xsq, TOKENS);
  conv_rows<<<VOCAB, 256, 0, stream>>>(w, Wb, bsq, VOCAB);

  for (int row0 = 0; row0 < TOKENS; row0 += TS) {
    dim3 g(VOCAB / BN, TS / BM);
    gemm_dist<<<g, 256, 0, stream>>>(Xb, Wb, xsq, bsq, dist, gmnE, gmxE, row0);
    select_topk<<<TS, 256, 0, stream>>>(dist, gmnE, gmxE, out, row0);
  }
}